// Round 3
// baseline (1575.784 us; speedup 1.0000x reference)
//
#include <hip/hip_runtime.h>

#define BATCH   512
#define TSTEPS  50
#define NIN     784
#define NHID    800
#define NOUT    10
#define KC      384   // OpenBLAS SGEMM_DEFAULT_Q (Zen/Haswell target)

// ---------------------------------------------------------------------------
// f32 GEMM (NT) replicating OpenBLAS sgemm rounding per output element:
//   for each KC-panel (ascending): partial = ascending-k FMA chain from 0
//   C[m,n] = ((P1 + P2) + P3)   (f32 adds, panel order)
// A: [M,K] f32 row-major, B: [N,K] f32 row-major (i.e. computes A @ B^T).
// 64x64 tile, 16-wide k-chunks (16 | KC and 16 | K-768 for K=784,800).
// M must be divisible by 64. No bias (added in scan, as in reference).
// ---------------------------------------------------------------------------
__global__ __launch_bounds__(256)
void gemm_nt_f32(const float* __restrict__ A, const float* __restrict__ B,
                 float* __restrict__ C, int M, int N, int K)
{
    __shared__ float As[64][21];
    __shared__ float Bs[64][21];

    const int tid = threadIdx.x;
    const int tx = tid & 15;        // n micro
    const int ty = tid >> 4;        // m micro
    const int m0 = blockIdx.y * 64;
    const int n0 = blockIdx.x * 64;

    const int lrow = tid >> 2;      // 0..63
    const int lk   = (tid & 3) * 4; // 0,4,8,12

    const float* Arow = A + (size_t)(m0 + lrow) * K + lk;
    const float* Brow = B + (size_t)(n0 + lrow) * K + lk;
    const bool bvalid = (n0 + lrow) < N;

    float acc[4][4];

    for (int p0 = 0; p0 < K; p0 += KC) {
        const int pend = (p0 + KC < K) ? (p0 + KC) : K;
        float part[4][4] = {};

        for (int k0 = p0; k0 < pend; k0 += 16) {
            float4 av = *(const float4*)(Arow + k0);
            float4 bv = bvalid ? *(const float4*)(Brow + k0)
                               : make_float4(0.f, 0.f, 0.f, 0.f);
            __syncthreads();
            As[lrow][lk+0] = av.x; As[lrow][lk+1] = av.y;
            As[lrow][lk+2] = av.z; As[lrow][lk+3] = av.w;
            Bs[lrow][lk+0] = bv.x; Bs[lrow][lk+1] = bv.y;
            Bs[lrow][lk+2] = bv.z; Bs[lrow][lk+3] = bv.w;
            __syncthreads();
            #pragma unroll
            for (int kk = 0; kk < 16; ++kk) {
                float a[4], b[4];
                #pragma unroll
                for (int i = 0; i < 4; ++i) a[i] = As[4*ty+i][kk];
                #pragma unroll
                for (int j = 0; j < 4; ++j) b[j] = Bs[4*tx+j][kk];
                #pragma unroll
                for (int i = 0; i < 4; ++i)
                    #pragma unroll
                    for (int j = 0; j < 4; ++j)
                        part[i][j] = __fmaf_rn(a[i], b[j], part[i][j]);
            }
        }

        #pragma unroll
        for (int i = 0; i < 4; ++i)
            #pragma unroll
            for (int j = 0; j < 4; ++j)
                acc[i][j] = (p0 == 0) ? part[i][j]
                                      : __fadd_rn(acc[i][j], part[i][j]);
    }

    #pragma unroll
    for (int i = 0; i < 4; ++i) {
        int m = m0 + 4*ty + i;
        #pragma unroll
        for (int j = 0; j < 4; ++j) {
            int n = n0 + 4*tx + j;
            if (n < N)
                C[(size_t)m * N + n] = acc[i][j];
        }
    }
}

// ---------------------------------------------------------------------------
// Small-N GEMM (layer 3): one thread per output element, same panel rounding.
// ---------------------------------------------------------------------------
__global__ __launch_bounds__(256)
void gemm3_f32(const float* __restrict__ S2,   // [rows, 800]
               const float* __restrict__ W3,   // [10, 800]
               float* __restrict__ Z3,         // [rows, 10]
               int rows)
{
    int gid = blockIdx.x * 256 + threadIdx.x;
    if (gid >= rows * NOUT) return;
    const int m = gid / NOUT;
    const int n = gid % NOUT;
    const float* a = S2 + (size_t)m * NHID;
    const float* w = W3 + (size_t)n * NHID;

    float acc = 0.0f;
    for (int p0 = 0; p0 < NHID; p0 += KC) {
        const int pend = (p0 + KC < NHID) ? (p0 + KC) : NHID;
        float part = 0.0f;
        for (int k = p0; k < pend; ++k)
            part = __fmaf_rn(a[k], w[k], part);
        acc = (p0 == 0) ? part : __fadd_rn(acc, part);
    }
    Z3[gid] = acc;
}

// ---------------------------------------------------------------------------
// Elementwise LIF scan, pure f32, numpy-faithful:
//   m = ((0.95f*m) + z) + b[j];  s = (m > thr);  m *= (1-s)
// ---------------------------------------------------------------------------
__global__ __launch_bounds__(256)
void lif_scan(const float* __restrict__ Z,      // [CT, BATCH*Nn]  (dot only)
              const float* __restrict__ bias,   // [Nn]
              const float* __restrict__ budget, // [Nn] or nullptr (thr = 1)
              float* __restrict__ mcarry,       // [BATCH*Nn]
              float* __restrict__ Sout,         // [TSTEPS, BATCH*Nn]
              int CT, int Nn, int t0)
{
    const int idx = blockIdx.x * blockDim.x + threadIdx.x;
    const int total = BATCH * Nn;
    if (idx >= total) return;
    const int j = idx % Nn;

    float thr = 1.0f;
    if (budget) {
        float bu = budget[j];
        bu = fminf(fmaxf(bu, 0.01f), 1.0f);   // np.clip(b, 0.01, 1.0) in f32
        thr = __fdiv_rn(1.0f, bu);            // correctly-rounded f32 divide
    }
    const float bj = bias[j];

    float m = mcarry[idx];
    for (int ct = 0; ct < CT; ++ct) {
        float z = Z[(size_t)ct * total + idx];
        m = __fadd_rn(__fadd_rn(__fmul_rn(0.95f, m), z), bj);
        float s;
        if (m > thr) { s = 1.0f; m = 0.0f; }
        else         { s = 0.0f; }
        Sout[(size_t)(t0 + ct) * total + idx] = s;
    }
    mcarry[idx] = m;
}

// ---------------------------------------------------------------------------
// out0[b, n] = sum_t s3[t, b, n]   (small integers — exact in f32, any order)
// ---------------------------------------------------------------------------
__global__ __launch_bounds__(256)
void sum_t(const float* __restrict__ S3, float* __restrict__ out0)
{
    const int idx = blockIdx.x * blockDim.x + threadIdx.x;
    if (idx >= BATCH * NOUT) return;
    float s = 0.0f;
    for (int t = 0; t < TSTEPS; ++t)
        s += S3[(size_t)t * BATCH * NOUT + idx];
    out0[idx] = s;
}

// ---------------------------------------------------------------------------
extern "C" void kernel_launch(void* const* d_in, const int* in_sizes, int n_in,
                              void* d_out, int out_size, void* d_ws, size_t ws_size,
                              hipStream_t stream)
{
    const float* x       = (const float*)d_in[0];  // [50, 512, 784]
    const float* W1      = (const float*)d_in[1];  // [800, 784]
    const float* b1      = (const float*)d_in[2];  // [800]
    const float* W2      = (const float*)d_in[3];  // [800, 800]
    const float* b2      = (const float*)d_in[4];  // [800]
    const float* W3      = (const float*)d_in[5];  // [10, 800]
    const float* b3      = (const float*)d_in[6];  // [10]
    const float* budget1 = (const float*)d_in[7];  // [800]
    const float* budget2 = (const float*)d_in[8];  // [800]

    float* out  = (float*)d_out;
    float* out0 = out;                                   // [512, 10]
    float* out1 = out0 + BATCH * NOUT;                   // [50, 512, 800]
    float* out2 = out1 + (size_t)TSTEPS * BATCH * NHID;  // [50, 512, 800]
    float* out3 = out2 + (size_t)TSTEPS * BATCH * NHID;  // [50, 512, 10]

    // workspace layout (floats)
    const size_t nBH   = (size_t)BATCH * NHID;   // 409600
    const size_t nBO   = (size_t)BATCH * NOUT;   // 5120
    const size_t carry = nBH * 2 + nBO;
    float* m1c = (float*)d_ws;
    float* m2c = m1c + nBH;
    float* m3c = m2c + nBH;
    float* Z   = m3c + nBO;

    // chunk size over T that fits in workspace
    size_t availF = (ws_size / 4 > carry) ? (ws_size / 4 - carry) : 0;
    size_t perT   = (size_t)BATCH * (NHID + NOUT);
    int CT = (int)(availF / perT);
    if (CT > TSTEPS) CT = TSTEPS;
    if (CT < 1) CT = 1;

    hipMemsetAsync(d_ws, 0, carry * sizeof(float), stream);

    for (int t0 = 0; t0 < TSTEPS; t0 += CT) {
        int ct = TSTEPS - t0 < CT ? TSTEPS - t0 : CT;
        int Mrows = ct * BATCH;
        float* Z3 = Z + (size_t)ct * BATCH * NHID;

        // layer 1: Z = x_chunk @ W1^T
        {
            dim3 grid((NHID + 63) / 64, Mrows / 64);
            gemm_nt_f32<<<grid, 256, 0, stream>>>(
                x + (size_t)t0 * BATCH * NIN, W1, Z, Mrows, NHID, NIN);
        }
        lif_scan<<<(BATCH * NHID + 255) / 256, 256, 0, stream>>>(
            Z, b1, budget1, m1c, out1, ct, NHID, t0);

        // layer 2: Z = s1_chunk @ W2^T
        {
            dim3 grid((NHID + 63) / 64, Mrows / 64);
            gemm_nt_f32<<<grid, 256, 0, stream>>>(
                out1 + (size_t)t0 * BATCH * NHID, W2, Z, Mrows, NHID, NHID);
        }
        lif_scan<<<(BATCH * NHID + 255) / 256, 256, 0, stream>>>(
            Z, b2, budget2, m2c, out2, ct, NHID, t0);

        // layer 3: Z3 = s2_chunk @ W3^T
        gemm3_f32<<<(Mrows * NOUT + 255) / 256, 256, 0, stream>>>(
            out2 + (size_t)t0 * BATCH * NHID, W3, Z3, Mrows);
        lif_scan<<<(BATCH * NOUT + 255) / 256, 256, 0, stream>>>(
            Z3, b3, nullptr, m3c, out3, ct, NOUT, t0);
    }

    sum_t<<<(BATCH * NOUT + 255) / 256, 256, 0, stream>>>(out3, out0);
}

// Round 4
// 1367.148 us; speedup vs baseline: 1.1526x; 1.1526x over previous
//
#include <hip/hip_runtime.h>

#define BATCH   512
#define TSTEPS  50
#define NIN     784
#define NHID    800
#define NOUT    10
#define KC      384   // OpenBLAS SGEMM_DEFAULT_Q (Zen/Haswell target)

// ---------------------------------------------------------------------------
// f32 GEMM (NT) replicating OpenBLAS sgemm rounding per output element:
//   per element: for each KC-panel (ascending), ascending-k FMA chain from 0;
//   C[m,n] = ((P1 + P2) + P3) (f32 adds in panel order).
// A: [M,K] f32 row-major, B: [N,K] f32 row-major (computes A @ B^T).
// 128x128 block tile, 8x8 per thread, BK=8, k-major LDS, register prefetch.
// Requires M % 128 == 0 (M = ct*512), K % 8 == 0 (784, 800), K <= 1152.
// ---------------------------------------------------------------------------
__global__ __launch_bounds__(256)
void gemm_nt_f32(const float* __restrict__ A, const float* __restrict__ B,
                 float* __restrict__ C, int M, int N, int K)
{
    __shared__ float As[8][132];   // [k][m], pad 128+4
    __shared__ float Bs[8][132];   // [k][n]

    const int tid = threadIdx.x;
    const int tx = tid & 15;        // n micro (8 cols)
    const int ty = tid >> 4;        // m micro (8 rows)
    const int m0 = blockIdx.x * 128;
    const int n0 = blockIdx.y * 128;

    // staging: each thread loads one float4 of A and one of B per 8-k chunk
    const int srow = tid >> 1;          // 0..127
    const int skq  = (tid & 1) * 4;     // 0 or 4

    const float* Aptr = A + (size_t)(m0 + srow) * K + skq;
    const float* Bptr = B + (size_t)(n0 + srow) * K + skq;
    const bool bval = (n0 + srow) < N;

    float acc[8][8];    // sum of closed panels
    float part[8][8];   // current panel
    #pragma unroll
    for (int i = 0; i < 8; ++i)
        #pragma unroll
        for (int j = 0; j < 8; ++j) part[i][j] = 0.0f;

    float4 av = *(const float4*)(Aptr);
    float4 bv = bval ? *(const float4*)(Bptr) : make_float4(0.f,0.f,0.f,0.f);

    for (int k0 = 0; k0 < K; k0 += 8) {
        __syncthreads();
        As[skq+0][srow] = av.x; As[skq+1][srow] = av.y;
        As[skq+2][srow] = av.z; As[skq+3][srow] = av.w;
        Bs[skq+0][srow] = bv.x; Bs[skq+1][srow] = bv.y;
        Bs[skq+2][srow] = bv.z; Bs[skq+3][srow] = bv.w;
        __syncthreads();

        // prefetch next chunk (issued before compute so latency hides)
        if (k0 + 8 < K) {
            av = *(const float4*)(Aptr + k0 + 8);
            bv = bval ? *(const float4*)(Bptr + k0 + 8)
                      : make_float4(0.f,0.f,0.f,0.f);
        }

        // panel fold (uniform branch, k0 in {384, 768})
        if (k0 == 384 || k0 == 768) {
            #pragma unroll
            for (int i = 0; i < 8; ++i)
                #pragma unroll
                for (int j = 0; j < 8; ++j) {
                    acc[i][j] = (k0 == 384) ? part[i][j]
                                            : __fadd_rn(acc[i][j], part[i][j]);
                    part[i][j] = 0.0f;
                }
        }

        #pragma unroll
        for (int kk = 0; kk < 8; ++kk) {
            float a[8], b[8];
            *(float4*)&a[0] = *(const float4*)&As[kk][8*ty];
            *(float4*)&a[4] = *(const float4*)&As[kk][8*ty+4];
            *(float4*)&b[0] = *(const float4*)&Bs[kk][8*tx];
            *(float4*)&b[4] = *(const float4*)&Bs[kk][8*tx+4];
            #pragma unroll
            for (int i = 0; i < 8; ++i)
                #pragma unroll
                for (int j = 0; j < 8; ++j)
                    part[i][j] = __fmaf_rn(a[i], b[j], part[i][j]);
        }
    }

    // final fold: K<=384 -> single panel; else acc + part
    #pragma unroll
    for (int i = 0; i < 8; ++i)
        #pragma unroll
        for (int j = 0; j < 8; ++j)
            acc[i][j] = (K <= 384) ? part[i][j] : __fadd_rn(acc[i][j], part[i][j]);

    #pragma unroll
    for (int i = 0; i < 8; ++i) {
        const int m = m0 + 8*ty + i;
        float* crow = C + (size_t)m * N + n0 + 8*tx;
        const int nb = n0 + 8*tx;
        if (nb + 7 < N) {
            *(float4*)(crow)     = make_float4(acc[i][0], acc[i][1], acc[i][2], acc[i][3]);
            *(float4*)(crow + 4) = make_float4(acc[i][4], acc[i][5], acc[i][6], acc[i][7]);
        } else {
            #pragma unroll
            for (int j = 0; j < 8; ++j)
                if (nb + j < N) crow[j] = acc[i][j];
        }
    }
}

// ---------------------------------------------------------------------------
// Small-N GEMM (layer 3): one thread per output element, same panel rounding.
// ---------------------------------------------------------------------------
__global__ __launch_bounds__(256)
void gemm3_f32(const float* __restrict__ S2,   // [rows, 800]
               const float* __restrict__ W3,   // [10, 800]
               float* __restrict__ Z3,         // [rows, 10]
               int rows)
{
    int gid = blockIdx.x * 256 + threadIdx.x;
    if (gid >= rows * NOUT) return;
    const int m = gid / NOUT;
    const int n = gid % NOUT;
    const float* a = S2 + (size_t)m * NHID;
    const float* w = W3 + (size_t)n * NHID;

    float acc = 0.0f;
    for (int p0 = 0; p0 < NHID; p0 += KC) {
        const int pend = (p0 + KC < NHID) ? (p0 + KC) : NHID;
        float part = 0.0f;
        for (int k = p0; k < pend; ++k)
            part = __fmaf_rn(a[k], w[k], part);
        acc = (p0 == 0) ? part : __fadd_rn(acc, part);
    }
    Z3[gid] = acc;
}

// ---------------------------------------------------------------------------
// Elementwise LIF scan, pure f32, numpy-faithful:
//   m = ((0.95f*m) + z) + b[j];  s = (m > thr);  m *= (1-s)
// ---------------------------------------------------------------------------
__global__ __launch_bounds__(256)
void lif_scan(const float* __restrict__ Z,      // [CT, BATCH*Nn]  (dot only)
              const float* __restrict__ bias,   // [Nn]
              const float* __restrict__ budget, // [Nn] or nullptr (thr = 1)
              float* __restrict__ mcarry,       // [BATCH*Nn]
              float* __restrict__ Sout,         // [TSTEPS, BATCH*Nn]
              int CT, int Nn, int t0)
{
    const int idx = blockIdx.x * blockDim.x + threadIdx.x;
    const int total = BATCH * Nn;
    if (idx >= total) return;
    const int j = idx % Nn;

    float thr = 1.0f;
    if (budget) {
        float bu = budget[j];
        bu = fminf(fmaxf(bu, 0.01f), 1.0f);   // np.clip in f32
        thr = __fdiv_rn(1.0f, bu);            // correctly-rounded f32 divide
    }
    const float bj = bias[j];

    float m = mcarry[idx];
    for (int ct = 0; ct < CT; ++ct) {
        float z = Z[(size_t)ct * total + idx];
        m = __fadd_rn(__fadd_rn(__fmul_rn(0.95f, m), z), bj);
        float s;
        if (m > thr) { s = 1.0f; m = 0.0f; }
        else         { s = 0.0f; }
        Sout[(size_t)(t0 + ct) * total + idx] = s;
    }
    mcarry[idx] = m;
}

// ---------------------------------------------------------------------------
// out0[b, n] = sum_t s3[t, b, n]   (small integers — exact in f32)
// ---------------------------------------------------------------------------
__global__ __launch_bounds__(256)
void sum_t(const float* __restrict__ S3, float* __restrict__ out0)
{
    const int idx = blockIdx.x * blockDim.x + threadIdx.x;
    if (idx >= BATCH * NOUT) return;
    float s = 0.0f;
    for (int t = 0; t < TSTEPS; ++t)
        s += S3[(size_t)t * BATCH * NOUT + idx];
    out0[idx] = s;
}

// ---------------------------------------------------------------------------
extern "C" void kernel_launch(void* const* d_in, const int* in_sizes, int n_in,
                              void* d_out, int out_size, void* d_ws, size_t ws_size,
                              hipStream_t stream)
{
    const float* x       = (const float*)d_in[0];  // [50, 512, 784]
    const float* W1      = (const float*)d_in[1];  // [800, 784]
    const float* b1      = (const float*)d_in[2];  // [800]
    const float* W2      = (const float*)d_in[3];  // [800, 800]
    const float* b2      = (const float*)d_in[4];  // [800]
    const float* W3      = (const float*)d_in[5];  // [10, 800]
    const float* b3      = (const float*)d_in[6];  // [10]
    const float* budget1 = (const float*)d_in[7];  // [800]
    const float* budget2 = (const float*)d_in[8];  // [800]

    float* out  = (float*)d_out;
    float* out0 = out;                                   // [512, 10]
    float* out1 = out0 + BATCH * NOUT;                   // [50, 512, 800]
    float* out2 = out1 + (size_t)TSTEPS * BATCH * NHID;  // [50, 512, 800]
    float* out3 = out2 + (size_t)TSTEPS * BATCH * NHID;  // [50, 512, 10]

    // workspace layout (floats)
    const size_t nBH   = (size_t)BATCH * NHID;   // 409600
    const size_t nBO   = (size_t)BATCH * NOUT;   // 5120
    const size_t carry = nBH * 2 + nBO;
    float* m1c = (float*)d_ws;
    float* m2c = m1c + nBH;
    float* m3c = m2c + nBH;
    float* Z   = m3c + nBO;

    // chunk size over T that fits in workspace
    size_t availF = (ws_size / 4 > carry) ? (ws_size / 4 - carry) : 0;
    size_t perT   = (size_t)BATCH * (NHID + NOUT);
    int CT = (int)(availF / perT);
    if (CT > TSTEPS) CT = TSTEPS;
    if (CT < 1) CT = 1;

    hipMemsetAsync(d_ws, 0, carry * sizeof(float), stream);

    for (int t0 = 0; t0 < TSTEPS; t0 += CT) {
        int ct = TSTEPS - t0 < CT ? TSTEPS - t0 : CT;
        int Mrows = ct * BATCH;
        float* Z3 = Z + (size_t)ct * BATCH * NHID;

        // layer 1: Z = x_chunk @ W1^T
        {
            dim3 grid(Mrows / 128, (NHID + 127) / 128);
            gemm_nt_f32<<<grid, 256, 0, stream>>>(
                x + (size_t)t0 * BATCH * NIN, W1, Z, Mrows, NHID, NIN);
        }
        lif_scan<<<(BATCH * NHID + 255) / 256, 256, 0, stream>>>(
            Z, b1, budget1, m1c, out1, ct, NHID, t0);

        // layer 2: Z = s1_chunk @ W2^T
        {
            dim3 grid(Mrows / 128, (NHID + 127) / 128);
            gemm_nt_f32<<<grid, 256, 0, stream>>>(
                out1 + (size_t)t0 * BATCH * NHID, W2, Z, Mrows, NHID, NHID);
        }
        lif_scan<<<(BATCH * NHID + 255) / 256, 256, 0, stream>>>(
            Z, b2, budget2, m2c, out2, ct, NHID, t0);

        // layer 3: Z3 = s2_chunk @ W3^T
        gemm3_f32<<<(Mrows * NOUT + 255) / 256, 256, 0, stream>>>(
            out2 + (size_t)t0 * BATCH * NHID, W3, Z3, Mrows);
        lif_scan<<<(BATCH * NOUT + 255) / 256, 256, 0, stream>>>(
            Z3, b3, nullptr, m3c, out3, ct, NOUT, t0);
    }

    sum_t<<<(BATCH * NOUT + 255) / 256, 256, 0, stream>>>(out3, out0);
}

// Round 5
// 1076.936 us; speedup vs baseline: 1.4632x; 1.2695x over previous
//
#include <hip/hip_runtime.h>

#define BATCH   512
#define TSTEPS  50
#define NIN     784
#define NHID    800
#define NOUT    10
#define KC      384   // OpenBLAS SGEMM_DEFAULT_Q (Zen target) — panel folds at 384, 768

#define BM 128
#define BN 64
#define BK 8

// ---------------------------------------------------------------------------
// f32 GEMM (NT) replicating OpenBLAS sgemm rounding per output element:
//   per element: for each KC-panel (ascending), ascending-k FMA chain from 0;
//   C[m,n] = ((P1 + P2) + P3) (f32 adds in panel order).
// A: [M,K] f32 row-major, B: [N,K] f32 row-major (computes A @ B^T).
// 128x64 block tile, 8x4 micro, BK=8, k-major LDS, register prefetch.
// ~64 accumulator VGPRs/thread -> 5 waves/SIMD for latency hiding.
// Requires M % 128 == 0 (M = ct*512), K % 8 == 0, K <= 1152.
// ---------------------------------------------------------------------------
__global__ __launch_bounds__(256, 4)
void gemm_nt_f32(const float* __restrict__ A, const float* __restrict__ B,
                 float* __restrict__ C, int M, int N, int K)
{
    __shared__ float As[BK][BM + 4];   // [k][m], 8 x 132
    __shared__ float Bs[BK][BN + 4];   // [k][n], 8 x 68

    const int tid = threadIdx.x;
    const int tx = tid & 15;        // n micro: cols 4*tx .. 4*tx+3
    const int ty = tid >> 4;        // m micro: rows 8*ty .. 8*ty+7
    const int m0 = blockIdx.x * BM;
    const int n0 = blockIdx.y * BN;

    // A staging: row m0+(tid>>1), k-quad (tid&1)*4   (one float4)
    const int arow = tid >> 1;          // 0..127
    const int akq  = (tid & 1) * 4;     // 0 or 4
    // B staging: row n0+(tid>>2), k-pair (tid&3)*2   (one float2)
    const int brow = tid >> 2;          // 0..63
    const int bkq  = (tid & 3) * 2;     // 0,2,4,6

    const float* Aptr = A + (size_t)(m0 + arow) * K + akq;
    const float* Bptr = B + (size_t)(n0 + brow) * K + bkq;
    const bool bval = (n0 + brow) < N;

    float part[8][4];   // current KC-panel chain
    float acc[8][4];    // folded closed panels
    #pragma unroll
    for (int i = 0; i < 8; ++i)
        #pragma unroll
        for (int j = 0; j < 4; ++j) part[i][j] = 0.0f;

    float4 av = *(const float4*)(Aptr);
    float2 bv = bval ? *(const float2*)(Bptr) : make_float2(0.f, 0.f);

    for (int k0 = 0; k0 < K; k0 += BK) {
        __syncthreads();
        As[akq+0][arow] = av.x; As[akq+1][arow] = av.y;
        As[akq+2][arow] = av.z; As[akq+3][arow] = av.w;
        Bs[bkq+0][brow] = bv.x; Bs[bkq+1][brow] = bv.y;
        __syncthreads();

        // prefetch next chunk (hides under the 8x32 FMA block)
        if (k0 + BK < K) {
            av = *(const float4*)(Aptr + k0 + BK);
            bv = bval ? *(const float2*)(Bptr + k0 + BK) : make_float2(0.f, 0.f);
        }

        // KC-panel fold (uniform branch; k0 in {384, 768})
        if (k0 == 384 || k0 == 768) {
            #pragma unroll
            for (int i = 0; i < 8; ++i)
                #pragma unroll
                for (int j = 0; j < 4; ++j) {
                    acc[i][j] = (k0 == 384) ? part[i][j]
                                            : __fadd_rn(acc[i][j], part[i][j]);
                    part[i][j] = 0.0f;
                }
        }

        #pragma unroll
        for (int kk = 0; kk < BK; ++kk) {
            float a[8], b[4];
            *(float4*)&a[0] = *(const float4*)&As[kk][8*ty];
            *(float4*)&a[4] = *(const float4*)&As[kk][8*ty + 4];
            *(float4*)&b[0] = *(const float4*)&Bs[kk][4*tx];
            #pragma unroll
            for (int i = 0; i < 8; ++i)
                #pragma unroll
                for (int j = 0; j < 4; ++j)
                    part[i][j] = __fmaf_rn(a[i], b[j], part[i][j]);
        }
    }

    #pragma unroll
    for (int i = 0; i < 8; ++i)
        #pragma unroll
        for (int j = 0; j < 4; ++j)
            acc[i][j] = (K <= KC) ? part[i][j] : __fadd_rn(acc[i][j], part[i][j]);

    const int cb = n0 + 4*tx;
    #pragma unroll
    for (int i = 0; i < 8; ++i) {
        const int m = m0 + 8*ty + i;
        float* crow = C + (size_t)m * N + cb;
        if (cb + 3 < N) {
            *(float4*)crow = make_float4(acc[i][0], acc[i][1], acc[i][2], acc[i][3]);
        } else {
            #pragma unroll
            for (int j = 0; j < 4; ++j)
                if (cb + j < N) crow[j] = acc[i][j];
        }
    }
}

// ---------------------------------------------------------------------------
// Small-N GEMM (layer 3): one thread per output element, same panel rounding.
// ---------------------------------------------------------------------------
__global__ __launch_bounds__(256)
void gemm3_f32(const float* __restrict__ S2,   // [rows, 800]
               const float* __restrict__ W3,   // [10, 800]
               float* __restrict__ Z3,         // [rows, 10]
               int rows)
{
    int gid = blockIdx.x * 256 + threadIdx.x;
    if (gid >= rows * NOUT) return;
    const int m = gid / NOUT;
    const int n = gid % NOUT;
    const float* a = S2 + (size_t)m * NHID;
    const float* w = W3 + (size_t)n * NHID;

    float acc = 0.0f;
    for (int p0 = 0; p0 < NHID; p0 += KC) {
        const int pend = (p0 + KC < NHID) ? (p0 + KC) : NHID;
        float part = 0.0f;
        for (int k = p0; k < pend; ++k)
            part = __fmaf_rn(a[k], w[k], part);
        acc = (p0 == 0) ? part : __fadd_rn(acc, part);
    }
    Z3[gid] = acc;
}

// ---------------------------------------------------------------------------
// Elementwise LIF scan, pure f32, numpy-faithful:
//   m = ((0.95f*m) + z) + b[j];  s = (m > thr);  m *= (1-s)
// ---------------------------------------------------------------------------
__global__ __launch_bounds__(256)
void lif_scan(const float* __restrict__ Z,      // [CT, BATCH*Nn]  (dot only)
              const float* __restrict__ bias,   // [Nn]
              const float* __restrict__ budget, // [Nn] or nullptr (thr = 1)
              float* __restrict__ mcarry,       // [BATCH*Nn]
              float* __restrict__ Sout,         // [TSTEPS, BATCH*Nn]
              int CT, int Nn, int t0)
{
    const int idx = blockIdx.x * blockDim.x + threadIdx.x;
    const int total = BATCH * Nn;
    if (idx >= total) return;
    const int j = idx % Nn;

    float thr = 1.0f;
    if (budget) {
        float bu = budget[j];
        bu = fminf(fmaxf(bu, 0.01f), 1.0f);   // np.clip in f32
        thr = __fdiv_rn(1.0f, bu);            // correctly-rounded f32 divide
    }
    const float bj = bias[j];

    float m = mcarry[idx];
    for (int ct = 0; ct < CT; ++ct) {
        float z = Z[(size_t)ct * total + idx];
        m = __fadd_rn(__fadd_rn(__fmul_rn(0.95f, m), z), bj);
        float s;
        if (m > thr) { s = 1.0f; m = 0.0f; }
        else         { s = 0.0f; }
        Sout[(size_t)(t0 + ct) * total + idx] = s;
    }
    mcarry[idx] = m;
}

// ---------------------------------------------------------------------------
// out0[b, n] = sum_t s3[t, b, n]   (small integers — exact in f32)
// ---------------------------------------------------------------------------
__global__ __launch_bounds__(256)
void sum_t(const float* __restrict__ S3, float* __restrict__ out0)
{
    const int idx = blockIdx.x * blockDim.x + threadIdx.x;
    if (idx >= BATCH * NOUT) return;
    float s = 0.0f;
    for (int t = 0; t < TSTEPS; ++t)
        s += S3[(size_t)t * BATCH * NOUT + idx];
    out0[idx] = s;
}

// ---------------------------------------------------------------------------
extern "C" void kernel_launch(void* const* d_in, const int* in_sizes, int n_in,
                              void* d_out, int out_size, void* d_ws, size_t ws_size,
                              hipStream_t stream)
{
    const float* x       = (const float*)d_in[0];  // [50, 512, 784]
    const float* W1      = (const float*)d_in[1];  // [800, 784]
    const float* b1      = (const float*)d_in[2];  // [800]
    const float* W2      = (const float*)d_in[3];  // [800, 800]
    const float* b2      = (const float*)d_in[4];  // [800]
    const float* W3      = (const float*)d_in[5];  // [10, 800]
    const float* b3      = (const float*)d_in[6];  // [10]
    const float* budget1 = (const float*)d_in[7];  // [800]
    const float* budget2 = (const float*)d_in[8];  // [800]

    float* out  = (float*)d_out;
    float* out0 = out;                                   // [512, 10]
    float* out1 = out0 + BATCH * NOUT;                   // [50, 512, 800]
    float* out2 = out1 + (size_t)TSTEPS * BATCH * NHID;  // [50, 512, 800]
    float* out3 = out2 + (size_t)TSTEPS * BATCH * NHID;  // [50, 512, 10]

    // workspace layout (floats)
    const size_t nBH   = (size_t)BATCH * NHID;   // 409600
    const size_t nBO   = (size_t)BATCH * NOUT;   // 5120
    const size_t carry = nBH * 2 + nBO;
    float* m1c = (float*)d_ws;
    float* m2c = m1c + nBH;
    float* m3c = m2c + nBH;
    float* Z   = m3c + nBO;

    // chunk size over T that fits in workspace
    size_t availF = (ws_size / 4 > carry) ? (ws_size / 4 - carry) : 0;
    size_t perT   = (size_t)BATCH * (NHID + NOUT);
    int CT = (int)(availF / perT);
    if (CT > TSTEPS) CT = TSTEPS;
    if (CT < 1) CT = 1;

    hipMemsetAsync(d_ws, 0, carry * sizeof(float), stream);

    for (int t0 = 0; t0 < TSTEPS; t0 += CT) {
        int ct = TSTEPS - t0 < CT ? TSTEPS - t0 : CT;
        int Mrows = ct * BATCH;
        float* Z3 = Z + (size_t)ct * BATCH * NHID;

        // layer 1: Z = x_chunk @ W1^T
        {
            dim3 grid(Mrows / BM, (NHID + BN - 1) / BN);
            gemm_nt_f32<<<grid, 256, 0, stream>>>(
                x + (size_t)t0 * BATCH * NIN, W1, Z, Mrows, NHID, NIN);
        }
        lif_scan<<<(BATCH * NHID + 255) / 256, 256, 0, stream>>>(
            Z, b1, budget1, m1c, out1, ct, NHID, t0);

        // layer 2: Z = s1_chunk @ W2^T
        {
            dim3 grid(Mrows / BM, (NHID + BN - 1) / BN);
            gemm_nt_f32<<<grid, 256, 0, stream>>>(
                out1 + (size_t)t0 * BATCH * NHID, W2, Z, Mrows, NHID, NHID);
        }
        lif_scan<<<(BATCH * NHID + 255) / 256, 256, 0, stream>>>(
            Z, b2, budget2, m2c, out2, ct, NHID, t0);

        // layer 3: Z3 = s2_chunk @ W3^T
        gemm3_f32<<<(Mrows * NOUT + 255) / 256, 256, 0, stream>>>(
            out2 + (size_t)t0 * BATCH * NHID, W3, Z3, Mrows);
        lif_scan<<<(BATCH * NOUT + 255) / 256, 256, 0, stream>>>(
            Z3, b3, nullptr, m3c, out3, ct, NOUT, t0);
    }

    sum_t<<<(BATCH * NOUT + 255) / 256, 256, 0, stream>>>(out3, out0);
}

// Round 6
// 858.196 us; speedup vs baseline: 1.8362x; 1.2549x over previous
//
#include <hip/hip_runtime.h>

#define BATCH   512
#define TSTEPS  50
#define NIN     784
#define NHID    800
#define NOUT    10
#define KC      384   // OpenBLAS SGEMM_DEFAULT_Q — panel folds at k=384, 768

#define BM 128
#define BN 64
#define BK 8

// ---------------------------------------------------------------------------
// Dense f32 GEMM (NT), OpenBLAS-rounding-exact (used for layer 1).
// Per element: ascending-k FMA chain per KC-panel; C = ((P1+P2)+P3).
// ---------------------------------------------------------------------------
__global__ __launch_bounds__(256, 4)
void gemm_nt_f32(const float* __restrict__ A, const float* __restrict__ B,
                 float* __restrict__ C, int M, int N, int K)
{
    __shared__ float As[BK][BM + 4];
    __shared__ float Bs[BK][BN + 4];

    const int tid = threadIdx.x;
    const int tx = tid & 15;
    const int ty = tid >> 4;
    const int m0 = blockIdx.x * BM;
    const int n0 = blockIdx.y * BN;

    const int arow = tid >> 1;
    const int akq  = (tid & 1) * 4;
    const int brow = tid >> 2;
    const int bkq  = (tid & 3) * 2;

    const float* Aptr = A + (size_t)(m0 + arow) * K + akq;
    const float* Bptr = B + (size_t)(n0 + brow) * K + bkq;
    const bool bval = (n0 + brow) < N;

    float part[8][4];
    float acc[8][4];
    #pragma unroll
    for (int i = 0; i < 8; ++i)
        #pragma unroll
        for (int j = 0; j < 4; ++j) part[i][j] = 0.0f;

    float4 av = *(const float4*)(Aptr);
    float2 bv = bval ? *(const float2*)(Bptr) : make_float2(0.f, 0.f);

    for (int k0 = 0; k0 < K; k0 += BK) {
        __syncthreads();
        As[akq+0][arow] = av.x; As[akq+1][arow] = av.y;
        As[akq+2][arow] = av.z; As[akq+3][arow] = av.w;
        Bs[bkq+0][brow] = bv.x; Bs[bkq+1][brow] = bv.y;
        __syncthreads();

        if (k0 + BK < K) {
            av = *(const float4*)(Aptr + k0 + BK);
            bv = bval ? *(const float2*)(Bptr + k0 + BK) : make_float2(0.f, 0.f);
        }

        if (k0 == 384 || k0 == 768) {
            #pragma unroll
            for (int i = 0; i < 8; ++i)
                #pragma unroll
                for (int j = 0; j < 4; ++j) {
                    acc[i][j] = (k0 == 384) ? part[i][j]
                                            : __fadd_rn(acc[i][j], part[i][j]);
                    part[i][j] = 0.0f;
                }
        }

        #pragma unroll
        for (int kk = 0; kk < BK; ++kk) {
            float a[8], b[4];
            *(float4*)&a[0] = *(const float4*)&As[kk][8*ty];
            *(float4*)&a[4] = *(const float4*)&As[kk][8*ty + 4];
            *(float4*)&b[0] = *(const float4*)&Bs[kk][4*tx];
            #pragma unroll
            for (int i = 0; i < 8; ++i)
                #pragma unroll
                for (int j = 0; j < 4; ++j)
                    part[i][j] = __fmaf_rn(a[i], b[j], part[i][j]);
        }
    }

    #pragma unroll
    for (int i = 0; i < 8; ++i)
        #pragma unroll
        for (int j = 0; j < 4; ++j)
            acc[i][j] = (K <= KC) ? part[i][j] : __fadd_rn(acc[i][j], part[i][j]);

    const int cb = n0 + 4*tx;
    #pragma unroll
    for (int i = 0; i < 8; ++i) {
        const int m = m0 + 8*ty + i;
        float* crow = C + (size_t)m * N + cb;
        if (cb + 3 < N) {
            *(float4*)crow = make_float4(acc[i][0], acc[i][1], acc[i][2], acc[i][3]);
        } else {
            #pragma unroll
            for (int j = 0; j < 4; ++j)
                if (cb + j < N) crow[j] = acc[i][j];
        }
    }
}

// ---------------------------------------------------------------------------
// 800x800 transpose: W2T[k][n] = W2[n][k]
// ---------------------------------------------------------------------------
__global__ __launch_bounds__(256)
void transpose800(const float* __restrict__ W2, float* __restrict__ W2T)
{
    __shared__ float t[32][33];
    const int tx  = threadIdx.x & 31;
    const int ty8 = threadIdx.x >> 5;          // 0..7
    const int bx = blockIdx.x * 32, by = blockIdx.y * 32;

    #pragma unroll
    for (int r = 0; r < 4; ++r) {
        int a = ty8 + r * 8;
        t[a][tx] = W2[(size_t)(by + a) * 800 + bx + tx];
    }
    __syncthreads();
    #pragma unroll
    for (int r = 0; r < 4; ++r) {
        int a = ty8 + r * 8;
        W2T[(size_t)(bx + a) * 800 + by + tx] = t[tx][a];
    }
}

// ---------------------------------------------------------------------------
// LIF scan for hidden layers (Nn=800), block per batch row, emits spike
// bitmask via 64-aligned ballots (window W = j/64 = c*4 + wave).
// m = ((0.95f*m) + z) + b[j]; s = (m > thr); multiplicative reset.
// ---------------------------------------------------------------------------
__global__ __launch_bounds__(256)
void lif_scan_hid(const float* __restrict__ Z,      // [CT][512*800] dot-sums
                  const float* __restrict__ bias,
                  const float* __restrict__ budget,
                  float* __restrict__ mcarry,       // [512*800]
                  float* __restrict__ Sout,         // [TSTEPS][512*800]
                  unsigned long long* __restrict__ bm, // [CT*512][13] or null
                  int CT, int t0)
{
    const int b = blockIdx.x;          // 0..511
    const int tid = threadIdx.x;
    const int lane = tid & 63;
    const int wave = tid >> 6;

    float m[4], thr[4], bj[4];
    bool val[4];
    #pragma unroll
    for (int c = 0; c < 4; ++c) {
        const int j = c * 256 + tid;
        val[c] = (j < NHID);
        const int jj = val[c] ? j : 0;
        float bu = budget[jj];
        bu = fminf(fmaxf(bu, 0.01f), 1.0f);
        thr[c] = __fdiv_rn(1.0f, bu);
        bj[c]  = bias[jj];
        m[c]   = mcarry[b * NHID + jj];
    }

    for (int ct = 0; ct < CT; ++ct) {
        const size_t zbase = (size_t)ct * (BATCH * NHID) + (size_t)b * NHID;
        const size_t sbase = (size_t)(t0 + ct) * (BATCH * NHID) + (size_t)b * NHID;
        #pragma unroll
        for (int c = 0; c < 4; ++c) {
            const int j = c * 256 + tid;
            bool sp = false;
            if (val[c]) {
                float z = Z[zbase + j];
                float mm = __fadd_rn(__fadd_rn(__fmul_rn(0.95f, m[c]), z), bj[c]);
                sp = (mm > thr[c]);
                m[c] = sp ? 0.0f : mm;
                Sout[sbase + j] = sp ? 1.0f : 0.0f;
            }
            unsigned long long bits = __ballot(sp);
            if (bm && lane == 0) {
                const int W = c * 4 + wave;
                if (W < 13)
                    bm[((size_t)ct * BATCH + b) * 13 + W] = bits;
            }
        }
    }
    #pragma unroll
    for (int c = 0; c < 4; ++c)
        if (val[c]) mcarry[b * NHID + c * 256 + tid] = m[c];
}

// ---------------------------------------------------------------------------
// Sparse spike GEMM: Z[row][n] = panel-folded sum over active k of W2T[k][n].
// Bit-exact vs dense chain: fma(0,w,p)=p, fma(1,w,p)=fadd(p,w).
// Block per row; k-list is wave-uniform (no divergence).
// ---------------------------------------------------------------------------
__global__ __launch_bounds__(256)
void spmm_spikes(const unsigned long long* __restrict__ bm, // [rows][13]
                 const float* __restrict__ W2T,             // [800][800]
                 float* __restrict__ Z,                     // [rows][800]
                 int rows)
{
    __shared__ unsigned long long wbuf[13];
    __shared__ unsigned short list[NHID];
    __shared__ int offs[14];

    const int tid = threadIdx.x;
    const int lane = tid & 63;
    const int wave = tid >> 6;
    const int row = blockIdx.x;

    if (tid < 13) wbuf[tid] = bm[(size_t)row * 13 + tid];
    __syncthreads();
    if (tid == 0) {
        int o = 0;
        for (int w = 0; w < 13; ++w) { offs[w] = o; o += __popcll(wbuf[w]); }
        offs[13] = o;
    }
    __syncthreads();
    for (int W = wave; W < 13; W += 4) {
        const unsigned long long bits = wbuf[W];
        const int pre = __popcll(bits & ((1ull << lane) - 1ull));
        if ((bits >> lane) & 1ull)
            list[offs[W] + pre] = (unsigned short)(W * 64 + lane);
    }
    __syncthreads();
    const int nnz = offs[13];

    if (tid < 200) {
        const int n = 4 * tid;
        float p0 = 0.f, p1 = 0.f, p2 = 0.f, p3 = 0.f;
        float a0 = 0.f, a1 = 0.f, a2 = 0.f, a3 = 0.f;
        int p = 0, nextb = KC;          // 384 then 768 then "never"
        for (int i = 0; i < nnz; ++i) {
            const int k = list[i];
            while (k >= nextb) {
                if (p == 0) { a0 = p0; a1 = p1; a2 = p2; a3 = p3; }
                else {
                    a0 = __fadd_rn(a0, p0); a1 = __fadd_rn(a1, p1);
                    a2 = __fadd_rn(a2, p2); a3 = __fadd_rn(a3, p3);
                }
                p0 = p1 = p2 = p3 = 0.f; ++p;
                nextb = (nextb == KC) ? 2 * KC : 100000;
            }
            const float4 w = *(const float4*)(W2T + (size_t)k * NHID + n);
            p0 = __fadd_rn(p0, w.x); p1 = __fadd_rn(p1, w.y);
            p2 = __fadd_rn(p2, w.z); p3 = __fadd_rn(p3, w.w);
        }
        while (p < 3) {                 // close remaining panels (K=800 -> 3)
            if (p == 0) { a0 = p0; a1 = p1; a2 = p2; a3 = p3; }
            else {
                a0 = __fadd_rn(a0, p0); a1 = __fadd_rn(a1, p1);
                a2 = __fadd_rn(a2, p2); a3 = __fadd_rn(a3, p3);
            }
            p0 = p1 = p2 = p3 = 0.f; ++p;
        }
        *(float4*)(Z + (size_t)row * NHID + n) = make_float4(a0, a1, a2, a3);
    }
}

// ---------------------------------------------------------------------------
// Layer-3 GEMM: one thread per output element, same panel rounding.
// ---------------------------------------------------------------------------
__global__ __launch_bounds__(256)
void gemm3_f32(const float* __restrict__ S2, const float* __restrict__ W3,
               float* __restrict__ Z3, int rows)
{
    int gid = blockIdx.x * 256 + threadIdx.x;
    if (gid >= rows * NOUT) return;
    const int m = gid / NOUT;
    const int n = gid % NOUT;
    const float* a = S2 + (size_t)m * NHID;
    const float* w = W3 + (size_t)n * NHID;

    float acc = 0.0f;
    for (int p0 = 0; p0 < NHID; p0 += KC) {
        const int pend = (p0 + KC < NHID) ? (p0 + KC) : NHID;
        float part = 0.0f;
        for (int k = p0; k < pend; ++k)
            part = __fmaf_rn(a[k], w[k], part);
        acc = (p0 == 0) ? part : __fadd_rn(acc, part);
    }
    Z3[gid] = acc;
}

// ---------------------------------------------------------------------------
// Small LIF scan (layer 3, Nn=10), one thread per (b, j).
// ---------------------------------------------------------------------------
__global__ __launch_bounds__(256)
void lif_scan_small(const float* __restrict__ Z, const float* __restrict__ bias,
                    float* __restrict__ mcarry, float* __restrict__ Sout,
                    int CT, int t0)
{
    const int idx = blockIdx.x * blockDim.x + threadIdx.x;
    const int total = BATCH * NOUT;
    if (idx >= total) return;
    const int j = idx % NOUT;
    const float thr = 1.0f;
    const float bj = bias[j];

    float m = mcarry[idx];
    for (int ct = 0; ct < CT; ++ct) {
        float z = Z[(size_t)ct * total + idx];
        m = __fadd_rn(__fadd_rn(__fmul_rn(0.95f, m), z), bj);
        float s;
        if (m > thr) { s = 1.0f; m = 0.0f; }
        else         { s = 0.0f; }
        Sout[(size_t)(t0 + ct) * total + idx] = s;
    }
    mcarry[idx] = m;
}

// ---------------------------------------------------------------------------
__global__ __launch_bounds__(256)
void sum_t(const float* __restrict__ S3, float* __restrict__ out0)
{
    const int idx = blockIdx.x * blockDim.x + threadIdx.x;
    if (idx >= BATCH * NOUT) return;
    float s = 0.0f;
    for (int t = 0; t < TSTEPS; ++t)
        s += S3[(size_t)t * BATCH * NOUT + idx];
    out0[idx] = s;
}

// ---------------------------------------------------------------------------
extern "C" void kernel_launch(void* const* d_in, const int* in_sizes, int n_in,
                              void* d_out, int out_size, void* d_ws, size_t ws_size,
                              hipStream_t stream)
{
    const float* x       = (const float*)d_in[0];
    const float* W1      = (const float*)d_in[1];
    const float* b1      = (const float*)d_in[2];
    const float* W2      = (const float*)d_in[3];
    const float* b2      = (const float*)d_in[4];
    const float* W3      = (const float*)d_in[5];
    const float* b3      = (const float*)d_in[6];
    const float* budget1 = (const float*)d_in[7];
    const float* budget2 = (const float*)d_in[8];

    float* out  = (float*)d_out;
    float* out0 = out;
    float* out1 = out0 + BATCH * NOUT;
    float* out2 = out1 + (size_t)TSTEPS * BATCH * NHID;
    float* out3 = out2 + (size_t)TSTEPS * BATCH * NHID;

    // workspace layout (floats; all offsets 16B-aligned)
    const size_t nBH = (size_t)BATCH * NHID;     // 409600
    const size_t nBO = (size_t)BATCH * NOUT;     // 5120
    float* m1c = (float*)d_ws;
    float* m2c = m1c + nBH;
    float* m3c = m2c + nBH;                      // nBO
    float* w2t = m3c + nBO;                      // 640000
    unsigned long long* bmask = (unsigned long long*)(w2t + (size_t)NHID * NHID);
    float* Z = (float*)(bmask + (size_t)TSTEPS * BATCH * 13);   // rest

    const size_t fixedF = 2 * nBH + nBO + (size_t)NHID * NHID
                        + (size_t)TSTEPS * BATCH * 13 * 2;      // 2,129,920
    size_t availF = (ws_size / 4 > fixedF) ? (ws_size / 4 - fixedF) : 0;
    const size_t perT = (size_t)BATCH * (NHID + NOUT);
    int CT = (int)(availF / perT);
    if (CT > TSTEPS) CT = TSTEPS;
    if (CT < 1) CT = 1;

    hipMemsetAsync(d_ws, 0, (2 * nBH + nBO) * sizeof(float), stream);

    {
        dim3 tg(25, 25);
        transpose800<<<tg, 256, 0, stream>>>(W2, w2t);
    }

    for (int t0 = 0; t0 < TSTEPS; t0 += CT) {
        int ct = TSTEPS - t0 < CT ? TSTEPS - t0 : CT;
        int Mrows = ct * BATCH;
        float* Z3 = Z + (size_t)ct * BATCH * NHID;

        // layer 1: dense Z = x_chunk @ W1^T
        {
            dim3 grid(Mrows / BM, (NHID + BN - 1) / BN);
            gemm_nt_f32<<<grid, 256, 0, stream>>>(
                x + (size_t)t0 * BATCH * NIN, W1, Z, Mrows, NHID, NIN);
        }
        lif_scan_hid<<<BATCH, 256, 0, stream>>>(
            Z, b1, budget1, m1c, out1, bmask, ct, t0);

        // layer 2: sparse Z = s1_chunk @ W2^T via bitmask
        spmm_spikes<<<Mrows, 256, 0, stream>>>(bmask, w2t, Z, Mrows);
        lif_scan_hid<<<BATCH, 256, 0, stream>>>(
            Z, b2, budget2, m2c, out2, nullptr, ct, t0);

        // layer 3
        gemm3_f32<<<(Mrows * NOUT + 255) / 256, 256, 0, stream>>>(
            out2 + (size_t)t0 * BATCH * NHID, W3, Z3, Mrows);
        lif_scan_small<<<(BATCH * NOUT + 255) / 256, 256, 0, stream>>>(
            Z3, b3, m3c, out3, ct, t0);
    }

    sum_t<<<(BATCH * NOUT + 255) / 256, 256, 0, stream>>>(out3, out0);
}